// Round 1
// baseline (767.915 us; speedup 1.0000x reference)
//
#include <hip/hip_runtime.h>

// GADBase guided anisotropic diffusion on MI355X.
// B=2, C=3, H=W=1024, coarse 128x128 (8x8 pooling), 64 steps.
// Structure: min-reduce (shift) -> init (img0, cv, ch) -> 64x fused
// diffuse+adjust step kernels (ping-pong) -> finalize (subtract shift).
// Key insight: the adjust step is per-8x8-block local, so with cell-aligned
// tiles each step is ONE kernel with no cross-workgroup reduction; the cell
// mean is a single lane-pair shuffle (no LDS, no barriers in the hot loop).

#define BB 2
#define HH 1024
#define WW 1024
#define NPIX (HH * WW)          // 1<<20
#define CVN (1023 * 1024)       // per-batch cv/ch element count (both 1047552)
#define SHW (128 * 128)         // coarse pixels per batch
#define LL 0.24f
#define KK2 (0.03f * 0.03f)
#define EPSF 1e-8f
#define DEPSF 0.1f
#define NPRE 64

__global__ void min_kernel(const float* __restrict__ src, float* __restrict__ shiftOut) {
    // 32768 elements, 1 block x 256 threads
    int tid = threadIdx.x;
    float m = 1e30f;
    for (int i = tid; i < BB * SHW; i += 256) m = fminf(m, src[i]);
    for (int off = 32; off > 0; off >>= 1) m = fminf(m, __shfl_down(m, off));
    __shared__ float sm[4];
    if ((tid & 63) == 0) sm[tid >> 6] = m;
    __syncthreads();
    if (tid == 0) {
        float mm = fminf(fminf(sm[0], sm[1]), fminf(sm[2], sm[3]));
        shiftOut[0] = (mm <= DEPSF) ? DEPSF : 0.0f;
    }
}

__global__ void init_kernel(const float* __restrict__ guide, const float* __restrict__ yb,
                            const float* __restrict__ shiftPtr, float* __restrict__ img,
                            float* __restrict__ cv, float* __restrict__ ch) {
    int idx = blockIdx.x * blockDim.x + threadIdx.x;
    if (idx >= BB * NPIX) return;
    int b = idx >> 20;
    int p = idx & (NPIX - 1);
    int y = p >> 10;
    int x = p & 1023;
    const float* gb = guide + (size_t)b * 3 * NPIX;
    const float* yBb = yb + (size_t)b * NPIX;
    float c0 = yBb[p];
    img[(size_t)b * NPIX + p] = c0 + shiftPtr[0];
    // shift cancels in all finite differences, so cv/ch use raw y_bicubic.
    if (y < HH - 1) {
        float d = fabsf(gb[p + WW] - gb[p])
                + fabsf(gb[NPIX + p + WW] - gb[NPIX + p])
                + fabsf(gb[2 * NPIX + p + WW] - gb[2 * NPIX + p])
                + fabsf(yBb[p + WW] - c0);
        d *= 0.25f;
        cv[(size_t)b * CVN + y * WW + x] = 1.0f / (1.0f + (d * d) / KK2);
    }
    if (x < WW - 1) {
        float d = fabsf(gb[p + 1] - gb[p])
                + fabsf(gb[NPIX + p + 1] - gb[NPIX + p])
                + fabsf(gb[2 * NPIX + p + 1] - gb[2 * NPIX + p])
                + fabsf(yBb[p + 1] - c0);
        d *= 0.25f;
        ch[(size_t)b * CVN + y * 1023 + x] = 1.0f / (1.0f + (d * d) / KK2);
    }
}

// One full diffuse_step + adjust_step. Tile = 64 rows x 128 cols per block,
// 256 threads; each thread owns 8 rows x 4 cols = one half of one 8x8 coarse
// cell, so the cell mean needs only shfl_xor(.,1). No LDS, no barriers.
__launch_bounds__(256)
__global__ void step_kernel(const float* __restrict__ imin, float* __restrict__ imout,
                            const float* __restrict__ cv, const float* __restrict__ ch,
                            const float* __restrict__ src, const float* __restrict__ mask,
                            const float* __restrict__ shiftPtr) {
    int blk = blockIdx.x;
    int b = blk >> 7;            // 128 tiles per batch image
    int r = blk & 127;
    int tileY = r >> 3;          // 0..15 (64-row tiles)
    int tileX = r & 7;           // 0..7  (128-col tiles)
    int tid = threadIdx.x;
    int cyL = tid >> 5;          // 0..7 local cell-row
    int g = tid & 31;            // 0..31 quad index in x
    int x = tileX * 128 + g * 4;
    int ybase = tileY * 64 + cyL * 8;

    const float* im = imin + (size_t)b * NPIX;
    float* om = imout + (size_t)b * NPIX;
    const float* cvb = cv + (size_t)b * CVN;
    const float* chb = ch + (size_t)b * CVN;

    float4 nv[8];
    float csum = 0.f;
#pragma unroll
    for (int k = 0; k < 8; ++k) {
        int y = ybase + k;
        const float* row = im + y * WW + x;
        float4 c = *(const float4*)row;
        float4 acc = c;
        if (y < HH - 1) {
            float4 dn = *(const float4*)(row + WW);
            float4 cvd = *(const float4*)(cvb + y * WW + x);
            acc.x += LL * cvd.x * (dn.x - c.x);
            acc.y += LL * cvd.y * (dn.y - c.y);
            acc.z += LL * cvd.z * (dn.z - c.z);
            acc.w += LL * cvd.w * (dn.w - c.w);
        }
        if (y > 0) {
            float4 up = *(const float4*)(row - WW);
            float4 cvu = *(const float4*)(cvb + (y - 1) * WW + x);
            acc.x -= LL * cvu.x * (c.x - up.x);
            acc.y -= LL * cvu.y * (c.y - up.y);
            acc.z -= LL * cvu.z * (c.z - up.z);
            acc.w -= LL * cvu.w * (c.w - up.w);
        }
        const float* chrow = chb + y * 1023;
        float xl = (x > 0) ? row[-1] : 0.f;
        float xr = (x + 4 < WW) ? row[4] : 0.f;
        float chm = (x > 0) ? chrow[x - 1] : 0.f;
        float ch0 = chrow[x];        // x <= 1020 so always valid (< 1023)
        float ch1 = chrow[x + 1];
        float ch2 = chrow[x + 2];
        float ch3 = (x + 3 < WW - 1) ? chrow[x + 3] : 0.f;
        acc.x += LL * (ch0 * (c.y - c.x) - chm * (c.x - xl));
        acc.y += LL * (ch1 * (c.z - c.y) - ch0 * (c.y - c.x));
        acc.z += LL * (ch2 * (c.w - c.z) - ch1 * (c.z - c.y));
        acc.w += LL * (ch3 * (xr - c.w) - ch2 * (c.w - c.z));
        nv[k] = acc;
        csum += acc.x + acc.y + acc.z + acc.w;
    }

    // 8x8 cell mean: this thread has 8x4 = half the cell; partner lane tid^1
    // has the other half (same cell). Both compute the same ratio.
    float osum = __shfl_xor(csum, 1);
    float mean = (csum + osum) * (1.0f / 64.0f);
    int sy = tileY * 8 + cyL;
    int sx = x >> 3;
    int sidx = b * SHW + sy * 128 + sx;
    float ratio;
    if (mask[sidx] < 0.5f) {
        ratio = 1.0f;
    } else {
        ratio = (src[sidx] + shiftPtr[0]) / (mean + EPSF);
    }
#pragma unroll
    for (int k = 0; k < 8; ++k) {
        float4 v = nv[k];
        v.x *= ratio; v.y *= ratio; v.z *= ratio; v.w *= ratio;
        *(float4*)(om + (size_t)(ybase + k) * WW + x) = v;
    }
}

__global__ void final_kernel(const float* __restrict__ img, const float* __restrict__ shiftPtr,
                             float* __restrict__ out) {
    int i = blockIdx.x * blockDim.x + threadIdx.x;  // over float4s, 524288 total
    float s = shiftPtr[0];
    float4 v = ((const float4*)img)[i];
    v.x -= s; v.y -= s; v.z -= s; v.w -= s;
    ((float4*)out)[i] = v;
}

extern "C" void kernel_launch(void* const* d_in, const int* in_sizes, int n_in,
                              void* d_out, int out_size, void* d_ws, size_t ws_size,
                              hipStream_t stream) {
    const float* guide = (const float*)d_in[0];   // [2,3,1024,1024]
    const float* yb    = (const float*)d_in[1];   // [2,1,1024,1024]
    const float* src   = (const float*)d_in[2];   // [2,1,128,128]
    const float* mask  = (const float*)d_in[3];   // [2,1,128,128]

    float* out = (float*)d_out;
    float* out_cv = out + (size_t)BB * NPIX;            // 2095104 elems
    float* out_ch = out_cv + (size_t)BB * CVN;          // 2095104 elems

    float* shift = (float*)d_ws;
    float* imgA = (float*)((char*)d_ws + 256);          // 8 MB ping buffer
    float* imgB = out;                                  // y_pred slot doubles as pong buffer

    min_kernel<<<1, 256, 0, stream>>>(src, shift);
    init_kernel<<<(BB * NPIX) / 256, 256, 0, stream>>>(guide, yb, shift, imgA, out_cv, out_ch);

    for (int t = 0; t < NPRE; ++t) {
        const float* in = (t & 1) ? imgB : imgA;
        float* o = (t & 1) ? imgA : imgB;
        step_kernel<<<BB * 128, 256, 0, stream>>>(in, o, out_cv, out_ch, src, mask, shift);
    }
    // NPRE=64 even: last step (t=63) read imgB, wrote imgA -> result in imgA.
    final_kernel<<<(BB * NPIX) / 4 / 256, 256, 0, stream>>>(imgA, shift, out);
}

// Round 2
// 585.739 us; speedup vs baseline: 1.3110x; 1.3110x over previous
//
#include <hip/hip_runtime.h>

// GADBase guided anisotropic diffusion on MI355X — round 2.
// B=2, H=W=1024, coarse 128x128 (8x8 pooling), 64 steps.
// R1 changes vs R0: rolling-register row reuse (3 float4 loads per k instead
// of ~12 mixed scalar/vector), padded cv (1025 rows, zero top/bottom) and
// padded ch (stride 1024, zero last col) in ws so no boundary branches on
// loads, x-halos via lane shuffles, 32-row tiles (512 blocks = 2/CU,
// 8 waves/CU), final shift-subtract folded into step 63.

#define BB 2
#define HH 1024
#define WW 1024
#define NPIX (HH * WW)          // 1<<20
#define CVN (1023 * 1024)       // compact cv/ch element count per batch
#define CVPN (1025 * 1024)      // padded cv rows per batch
#define SHW (128 * 128)
#define LL 0.24f
#define KK2 (0.03f * 0.03f)
#define EPSF 1e-8f
#define DEPSF 0.1f
#define NPRE 64

__global__ void min_kernel(const float* __restrict__ src, float* __restrict__ shiftOut) {
    int tid = threadIdx.x;
    float m = 1e30f;
    for (int i = tid; i < BB * SHW; i += 256) m = fminf(m, src[i]);
    for (int off = 32; off > 0; off >>= 1) m = fminf(m, __shfl_down(m, off));
    __shared__ float sm[4];
    if ((tid & 63) == 0) sm[tid >> 6] = m;
    __syncthreads();
    if (tid == 0) {
        float mm = fminf(fminf(sm[0], sm[1]), fminf(sm[2], sm[3]));
        shiftOut[0] = (mm <= DEPSF) ? DEPSF : 0.0f;
    }
}

__global__ void init_kernel(const float* __restrict__ guide, const float* __restrict__ yb,
                            const float* __restrict__ shiftPtr, float* __restrict__ img0,
                            float* __restrict__ cv_out, float* __restrict__ ch_out,
                            float* __restrict__ cvp, float* __restrict__ chp) {
    int idx = blockIdx.x * blockDim.x + threadIdx.x;
    if (idx >= BB * NPIX) return;
    int b = idx >> 20;
    int p = idx & (NPIX - 1);
    int y = p >> 10;
    int x = p & 1023;
    const float* gb = guide + (size_t)b * 3 * NPIX;
    const float* yBb = yb + (size_t)b * NPIX;
    float c0 = yBb[p];
    img0[(size_t)b * NPIX + p] = c0 + shiftPtr[0];
    // shift cancels in finite diffs -> cv/ch from raw y_bicubic.
    float* cvpb = cvp + (size_t)b * CVPN;
    float* chpb = chp + (size_t)b * NPIX;
    if (y < HH - 1) {
        float d = fabsf(gb[p + WW] - gb[p])
                + fabsf(gb[NPIX + p + WW] - gb[NPIX + p])
                + fabsf(gb[2 * NPIX + p + WW] - gb[2 * NPIX + p])
                + fabsf(yBb[p + WW] - c0);
        d *= 0.25f;
        float v = 1.0f / (1.0f + (d * d) / KK2);
        cv_out[(size_t)b * CVN + y * WW + x] = v;
        cvpb[(y + 1) * WW + x] = v;           // padded: row r holds cv[r-1]
    } else {
        cvpb[x] = 0.f;                        // row 0 (above top edge)
        cvpb[1024 * WW + x] = 0.f;            // row 1024 (below bottom edge)
    }
    if (x < WW - 1) {
        float d = fabsf(gb[p + 1] - gb[p])
                + fabsf(gb[NPIX + p + 1] - gb[NPIX + p])
                + fabsf(gb[2 * NPIX + p + 1] - gb[2 * NPIX + p])
                + fabsf(yBb[p + 1] - c0);
        d *= 0.25f;
        float v = 1.0f / (1.0f + (d * d) / KK2);
        ch_out[(size_t)b * CVN + y * 1023 + x] = v;
        chpb[y * WW + x] = v;                 // padded stride-1024
    } else {
        chpb[y * WW + 1023] = 0.f;            // zero conductance past right edge
    }
}

// One diffuse_step + adjust_step. Tile = 32 rows x 128 cols, 256 threads;
// thread owns 4 rows x 4 cols. 8x8 coarse cell = lanes {tid, tid^1, tid^32,
// tid^33} -> mean via shfl_xor(1)+shfl_xor(32). Rolling registers: each k
// loads 1 new im row, 1 cv row, 1 ch row (float4 each). No LDS, no barriers.
__launch_bounds__(256)
__global__ void step_kernel(const float* __restrict__ imin, float* __restrict__ imout,
                            const float* __restrict__ cvp, const float* __restrict__ chp,
                            const float* __restrict__ src, const float* __restrict__ mask,
                            const float* __restrict__ shiftPtr, int last) {
    int blk = blockIdx.x;
    int b = blk >> 8;            // 256 tiles per batch image
    int r = blk & 255;
    int tileY = r >> 3;          // 0..31 (32-row tiles)
    int tileX = r & 7;           // 0..7  (128-col tiles)
    int tid = threadIdx.x;
    int cyL = tid >> 5;          // 0..7 (4-row groups)
    int g = tid & 31;
    int x = tileX * 128 + g * 4;
    int y0 = tileY * 32 + cyL * 4;

    const float* im = imin + (size_t)b * NPIX;
    float* om = imout + (size_t)b * NPIX;
    const float* cvpb = cvp + (size_t)b * CVPN;
    const float* chpb = chp + (size_t)b * NPIX;

    int yUp = (y0 > 0) ? y0 - 1 : 0;              // value unused when cvUp==0
    float4 rUp = *(const float4*)(im + yUp * WW + x);
    float4 rC  = *(const float4*)(im + y0 * WW + x);
    float4 cvUp = *(const float4*)(cvpb + y0 * WW + x);   // cv[y0-1] (0 at top)

    float4 nv[4];
    float csum = 0.f;
#pragma unroll
    for (int k = 0; k < 4; ++k) {
        int y = y0 + k;
        int yDn = (y < HH - 1) ? y + 1 : y;       // clamped row; cvDn==0 there
        float4 rDn  = *(const float4*)(im + yDn * WW + x);
        float4 cvDn = *(const float4*)(cvpb + (y + 1) * WW + x);   // cv[y] (0 at bottom)
        float4 h4   = *(const float4*)(chpb + y * WW + x);         // ch[x..x+3], 0-padded
        float xl = __shfl_up(rC.w, 1);
        float xr = __shfl_down(rC.x, 1);
        float hm = __shfl_up(h4.w, 1);
        if (g == 0) {      // lanes 0,32: left neighbor is outside the 32-lane strip
            xl = (x > 0) ? im[y * WW + x - 1] : 0.f;
            hm = (x > 0) ? chpb[y * WW + x - 1] : 0.f;   // 0 at x==0 -> term dies
        }
        if (g == 31) {     // lanes 31,63: right neighbor outside strip
            xr = (x + 4 < WW) ? im[y * WW + x + 4] : 0.f; // h4.w==0 at right edge
        }
        float4 acc;
        acc.x = rC.x + LL * (cvDn.x * (rDn.x - rC.x) - cvUp.x * (rC.x - rUp.x)
                           + h4.x * (rC.y - rC.x) - hm   * (rC.x - xl));
        acc.y = rC.y + LL * (cvDn.y * (rDn.y - rC.y) - cvUp.y * (rC.y - rUp.y)
                           + h4.y * (rC.z - rC.y) - h4.x * (rC.y - rC.x));
        acc.z = rC.z + LL * (cvDn.z * (rDn.z - rC.z) - cvUp.z * (rC.z - rUp.z)
                           + h4.z * (rC.w - rC.z) - h4.y * (rC.z - rC.y));
        acc.w = rC.w + LL * (cvDn.w * (rDn.w - rC.w) - cvUp.w * (rC.w - rUp.w)
                           + h4.w * (xr   - rC.w) - h4.z * (rC.w - rC.z));
        nv[k] = acc;
        csum += acc.x + acc.y + acc.z + acc.w;
        rUp = rC; rC = rDn; cvUp = cvDn;
    }

    // 8x8 cell mean across the 4 owner lanes (all within one 64-lane wave).
    csum += __shfl_xor(csum, 1);
    csum += __shfl_xor(csum, 32);
    float mean = csum * (1.0f / 64.0f);
    int sy = tileY * 4 + (cyL >> 1);
    int sx = tileX * 16 + (g >> 1);
    int sidx = b * SHW + sy * 128 + sx;
    float shift = shiftPtr[0];
    float ratio = (mask[sidx] < 0.5f) ? 1.0f : (src[sidx] + shift) / (mean + EPSF);
    float sub = last ? shift : 0.0f;
#pragma unroll
    for (int k = 0; k < 4; ++k) {
        float4 v = nv[k];
        v.x = v.x * ratio - sub;
        v.y = v.y * ratio - sub;
        v.z = v.z * ratio - sub;
        v.w = v.w * ratio - sub;
        *(float4*)(om + (size_t)(y0 + k) * WW + x) = v;
    }
}

extern "C" void kernel_launch(void* const* d_in, const int* in_sizes, int n_in,
                              void* d_out, int out_size, void* d_ws, size_t ws_size,
                              hipStream_t stream) {
    const float* guide = (const float*)d_in[0];   // [2,3,1024,1024]
    const float* yb    = (const float*)d_in[1];   // [2,1,1024,1024]
    const float* src   = (const float*)d_in[2];   // [2,1,128,128]
    const float* mask  = (const float*)d_in[3];   // [2,1,128,128]

    float* out    = (float*)d_out;                       // y_pred slot (ping buffer)
    float* out_cv = out + (size_t)BB * NPIX;
    float* out_ch = out_cv + (size_t)BB * CVN;

    float* wsf  = (float*)d_ws;
    float* shift = wsf;                                  // [0]
    float* imgA  = wsf + 256;                            // 8 MB pong buffer
    float* cvp   = imgA + (size_t)BB * NPIX;             // padded cv: 2 x 1025 x 1024
    float* chp   = cvp + (size_t)BB * CVPN;              // padded ch: 2 x 1024 x 1024

    min_kernel<<<1, 256, 0, stream>>>(src, shift);
    init_kernel<<<(BB * NPIX) / 256, 256, 0, stream>>>(guide, yb, shift, out,
                                                       out_cv, out_ch, cvp, chp);

    // t even: out -> imgA ; t odd: imgA -> out. t=63 (odd) writes out with -shift.
    for (int t = 0; t < NPRE; ++t) {
        const float* in = (t & 1) ? imgA : out;
        float* o = (t & 1) ? out : imgA;
        step_kernel<<<BB * 256, 256, 0, stream>>>(in, o, cvp, chp, src, mask, shift,
                                                  (t == NPRE - 1) ? 1 : 0);
    }
}